// Round 5
// baseline (71.774 us; speedup 1.0000x reference)
//
#include <hip/hip_runtime.h>
#include <math.h>

// pred [65536, 1024] f32, target [65536] int32
static constexpr int N = 65536;
static constexpr int C = 1024;
static constexpr float EPS = 1e-9f;

// Math (validated absmax==0.0 in R4):
//   total = -log2e*C*(1+N*EPS) + log2e*SumX - SumLogS ;  loss = -total/(N*C)
//   SumX    = sum_t pred[n, tgt[n]]      (extracted in K1 from in-flight regs)
//   SumLogS = sum_t log2(S[tgt[n]])      (4 KB LDS table gather in K2)
//
// ws float layout:
//   [0..1023]   logS[C]      per-column log2(sum exp)  (written by K2, atomic st)
//   [1024]      counter      K2 arrival counter        (zeroed by K1 block 0)
//   [1088..]    sxArr[RB]    per-block partial SumX    (fully written by K1)
//   [4096..]    partial[RB][C] per-rowblock column partials (fully written by K1)

// ---------------------------------------------------------------------------
// K1: per-rowblock column partials of exp + target-value extraction.
// Thread t owns columns 4t..4t+3; one block-iteration row = 256 x 16 B = 4 KB
// coalesced. 8 independent float4 loads issue per batch before any consume
// (sched_barrier) -> 8 KB/wave of HBM requests in flight.
template <int RPB>
__global__ __launch_bounds__(256) void colsum_partial_kernel(
    const float* __restrict__ pred, const int* __restrict__ tgt,
    float* __restrict__ partial, float* __restrict__ sxArr,
    int* __restrict__ counter) {
    const int tid  = threadIdx.x;                  // 0..255
    const int row0 = blockIdx.x * RPB;
    if (blockIdx.x == 0 && tid == 0) *counter = 0; // replaces memset dispatch

    __shared__ int tgt_lds[RPB];
    if (tid < RPB) tgt_lds[tid] = tgt[row0 + tid];
    __syncthreads();

    const float4* __restrict__ p4 =
        reinterpret_cast<const float4*>(pred) + (size_t)row0 * (C / 4) + tid;

    float a0 = 0.f, a1 = 0.f, a2 = 0.f, a3 = 0.f;
    float sx = 0.f;
#pragma unroll 1
    for (int b = 0; b < RPB / 8; ++b) {
        float4 v0 = p4[0 * (C / 4)];
        float4 v1 = p4[1 * (C / 4)];
        float4 v2 = p4[2 * (C / 4)];
        float4 v3 = p4[3 * (C / 4)];
        float4 v4 = p4[4 * (C / 4)];
        float4 v5 = p4[5 * (C / 4)];
        float4 v6 = p4[6 * (C / 4)];
        float4 v7 = p4[7 * (C / 4)];
        p4 += 8 * (C / 4);
        __builtin_amdgcn_sched_barrier(0);         // all 8 loads issued first

#pragma unroll
        for (int r = 0; r < 8; ++r) {
            const int tc = tgt_lds[b * 8 + r];
            if ((tc >> 2) == tid) {
                const float4 v = (r == 0) ? v0 : (r == 1) ? v1 : (r == 2) ? v2
                               : (r == 3) ? v3 : (r == 4) ? v4 : (r == 5) ? v5
                               : (r == 6) ? v6 : v7;
                const int sel = tc & 3;
                sx += (sel == 0) ? v.x : (sel == 1) ? v.y : (sel == 2) ? v.z : v.w;
            }
        }

        a0 += __expf(v0.x) + __expf(v1.x) + __expf(v2.x) + __expf(v3.x)
            + __expf(v4.x) + __expf(v5.x) + __expf(v6.x) + __expf(v7.x);
        a1 += __expf(v0.y) + __expf(v1.y) + __expf(v2.y) + __expf(v3.y)
            + __expf(v4.y) + __expf(v5.y) + __expf(v6.y) + __expf(v7.y);
        a2 += __expf(v0.z) + __expf(v1.z) + __expf(v2.z) + __expf(v3.z)
            + __expf(v4.z) + __expf(v5.z) + __expf(v6.z) + __expf(v7.z);
        a3 += __expf(v0.w) + __expf(v1.w) + __expf(v2.w) + __expf(v3.w)
            + __expf(v4.w) + __expf(v5.w) + __expf(v6.w) + __expf(v7.w);
    }

    reinterpret_cast<float4*>(partial + (size_t)blockIdx.x * C)[tid] =
        make_float4(a0, a1, a2, a3);

#pragma unroll
    for (int off = 32; off > 0; off >>= 1)
        sx += __shfl_down(sx, off, 64);
    __shared__ float wsum[4];
    if ((tid & 63) == 0) wsum[tid >> 6] = sx;
    __syncthreads();
    if (tid == 0)
        sxArr[blockIdx.x] = wsum[0] + wsum[1] + wsum[2] + wsum[3];
}

// ---------------------------------------------------------------------------
// K2 (fused reduce + gather + finalize), 64 blocks x 256 threads.
// Each block OWNS 16 columns: reduces RB partial rows (float2 loads, 8
// independent accumulator streams, full-64B-line coalescing per wave), writes
// log2(S_c) with agent-scope release stores (no atomics-into-S, no memset).
// Arrival counter; the last block agent-acquires, stages logS in LDS, gathers
// all N targets from LDS, sums sxArr, finalizes in double.
__global__ __launch_bounds__(256) void reduce_gather_kernel(
    const float* __restrict__ partial, const int* __restrict__ tgt,
    const float* __restrict__ sxArr, float* __restrict__ logS,
    int* __restrict__ counter, float* __restrict__ out, int RB) {
    const int t  = threadIdx.x;
    const int cp = t & 7;          // column-pair slot within the 16-col group
    const int r0 = t >> 3;         // 0..31
    const int c0 = blockIdx.x * 16;
    const int eighth = RB / 8;     // RB in {512,1024,2048} -> 64/128/256

    const float2* __restrict__ p2 =
        reinterpret_cast<const float2*>(partial) + (c0 >> 1) + cp;

    float2 a[8];
#pragma unroll
    for (int j = 0; j < 8; ++j) a[j] = make_float2(0.f, 0.f);
    for (int r = r0; r < eighth; r += 32) {
#pragma unroll
        for (int j = 0; j < 8; ++j) {
            const float2 v = p2[(size_t)(r + j * eighth) * (C / 2)];
            a[j].x += v.x;
            a[j].y += v.y;
        }
    }
    float2 s;
    s.x = ((a[0].x + a[1].x) + (a[2].x + a[3].x)) + ((a[4].x + a[5].x) + (a[6].x + a[7].x));
    s.y = ((a[0].y + a[1].y) + (a[2].y + a[3].y)) + ((a[4].y + a[5].y) + (a[6].y + a[7].y));
#pragma unroll
    for (int off = 8; off <= 32; off <<= 1) {
        s.x += __shfl_xor(s.x, off, 64);
        s.y += __shfl_xor(s.y, off, 64);
    }
    __shared__ float2 wred[4][8];
    if ((t & 63) < 8) wred[t >> 6][cp] = s;
    __syncthreads();
    if (t < 8) {
        const float vx = wred[0][t].x + wred[1][t].x + wred[2][t].x + wred[3][t].x;
        const float vy = wred[0][t].y + wred[1][t].y + wred[2][t].y + wred[3][t].y;
        __hip_atomic_store(&logS[c0 + 2 * t],     log2f(vx),
                           __ATOMIC_RELEASE, __HIP_MEMORY_SCOPE_AGENT);
        __hip_atomic_store(&logS[c0 + 2 * t + 1], log2f(vy),
                           __ATOMIC_RELEASE, __HIP_MEMORY_SCOPE_AGENT);
        __threadfence();           // push to coherent point before arrival
    }
    __syncthreads();

    __shared__ int last;
    if (t == 0) {
        const int old = __hip_atomic_fetch_add(counter, 1, __ATOMIC_ACQ_REL,
                                               __HIP_MEMORY_SCOPE_AGENT);
        last = (old == (int)gridDim.x - 1) ? 1 : 0;
    }
    __syncthreads();
    if (!last) return;

    // ---- last block only: stage logS in LDS (agent-scope loads dodge any
    // stale per-XCD cache), gather all targets, finalize.
    __shared__ float lut[C];
    for (int i = t; i < C; i += 256)
        lut[i] = __hip_atomic_load(&logS[i], __ATOMIC_RELAXED,
                                   __HIP_MEMORY_SCOPE_AGENT);
    __syncthreads();

    float accL = 0.f;
    for (int n = t; n < N; n += 256 * 8) {      // 32 iters, 8 indep loads each
        accL += lut[tgt[n + 256 * 0]] + lut[tgt[n + 256 * 1]]
              + lut[tgt[n + 256 * 2]] + lut[tgt[n + 256 * 3]]
              + lut[tgt[n + 256 * 4]] + lut[tgt[n + 256 * 5]]
              + lut[tgt[n + 256 * 6]] + lut[tgt[n + 256 * 7]];
    }
    float sx = 0.f;
    for (int i = t; i < RB; i += 256) sx += sxArr[i];

#pragma unroll
    for (int off = 32; off > 0; off >>= 1) {
        accL += __shfl_down(accL, off, 64);
        sx   += __shfl_down(sx, off, 64);
    }
    __shared__ float r1[4], r2[4];
    if ((t & 63) == 0) { r1[t >> 6] = accL; r2[t >> 6] = sx; }
    __syncthreads();
    if (t == 0) {
        const double LOG2E = 1.4426950408889634;
        const double SumLogS = (double)(r1[0] + r1[1] + r1[2] + r1[3]);
        const double SumX    = (double)(r2[0] + r2[1] + r2[2] + r2[3]);
        const double termA   = -LOG2E * (double)C * (1.0 + (double)N * (double)EPS);
        const double total   = termA + LOG2E * SumX - SumLogS;
        out[0] = (float)(-total / ((double)N * (double)C));
    }
}

extern "C" void kernel_launch(void* const* d_in, const int* in_sizes, int n_in,
                              void* d_out, int out_size, void* d_ws, size_t ws_size,
                              hipStream_t stream) {
    const float* pred = (const float*)d_in[0];
    const int*   tgt  = (const int*)d_in[1];
    float* wsf     = (float*)d_ws;
    float* logS    = wsf;
    int*   counter = (int*)(wsf + 1024);
    float* sxArr   = wsf + 1088;
    float* partial = wsf + 4096;               // 16 KB offset, 16B-aligned
    const size_t base_bytes = 4096 * sizeof(float);

    int RB = 2048;
    while (RB > 512 && base_bytes + (size_t)RB * C * sizeof(float) > ws_size)
        RB >>= 1;

    if (RB >= 2048)
        colsum_partial_kernel<32><<<2048, 256, 0, stream>>>(pred, tgt, partial, sxArr, counter);
    else if (RB == 1024)
        colsum_partial_kernel<64><<<1024, 256, 0, stream>>>(pred, tgt, partial, sxArr, counter);
    else
        colsum_partial_kernel<128><<<512, 256, 0, stream>>>(pred, tgt, partial, sxArr, counter);

    reduce_gather_kernel<<<64, 256, 0, stream>>>(partial, tgt, sxArr, logS,
                                                 counter, (float*)d_out, RB);
}

// Round 6
// 65.033 us; speedup vs baseline: 1.1036x; 1.1036x over previous
//
#include <hip/hip_runtime.h>
#include <math.h>

// pred [65536, 1024] f32, target [65536] int32
static constexpr int N = 65536;
static constexpr int C = 1024;
static constexpr float EPS = 1e-9f;

// Math (validated absmax==0.0 in R4/R5):
//   total = -log2e*C*(1+N*EPS) + log2e*SumX - SumLogS ;  loss = -total/(N*C)
//   SumX    = sum_t pred[n, tgt[n]]      (extracted in K1 from in-flight regs)
//   SumLogS = sum_t log2(S[tgt[n]])      (gather from 4 KB logS table)
//
// ws float layout (no pre-zeroing needed: no atomic accumulators anywhere):
//   [0..1023]   logS[C]        written by K2 (plain owned-column stores)
//   [1024]      counter        zeroed by K1 block 0; K3 arrival counter
//   [1088..]    sxArr[RB]      per-block partial SumX (fully written by K1)
//   [3200..]    gArr[256]      per-block partial SumLogS (fully written by K3)
//   [4096..]    partial[RB][C] per-rowblock column partials (written by K1)

// ---------------------------------------------------------------------------
// K1: per-rowblock column partials of exp + target-value extraction.
// Thread t owns columns 4t..4t+3; one block-iteration row = 256 x 16 B = 4 KB
// coalesced. 8 independent float4 loads issue per batch before any consume
// (sched_barrier) -> 8 KB/wave of HBM requests in flight. (R4 known-good.)
template <int RPB>
__global__ __launch_bounds__(256) void colsum_partial_kernel(
    const float* __restrict__ pred, const int* __restrict__ tgt,
    float* __restrict__ partial, float* __restrict__ sxArr,
    int* __restrict__ counter) {
    const int tid  = threadIdx.x;                  // 0..255
    const int row0 = blockIdx.x * RPB;
    if (blockIdx.x == 0 && tid == 0) *counter = 0; // for K3's arrival counter

    __shared__ int tgt_lds[RPB];
    if (tid < RPB) tgt_lds[tid] = tgt[row0 + tid];
    __syncthreads();

    const float4* __restrict__ p4 =
        reinterpret_cast<const float4*>(pred) + (size_t)row0 * (C / 4) + tid;

    float a0 = 0.f, a1 = 0.f, a2 = 0.f, a3 = 0.f;
    float sx = 0.f;
#pragma unroll 1
    for (int b = 0; b < RPB / 8; ++b) {
        float4 v0 = p4[0 * (C / 4)];
        float4 v1 = p4[1 * (C / 4)];
        float4 v2 = p4[2 * (C / 4)];
        float4 v3 = p4[3 * (C / 4)];
        float4 v4 = p4[4 * (C / 4)];
        float4 v5 = p4[5 * (C / 4)];
        float4 v6 = p4[6 * (C / 4)];
        float4 v7 = p4[7 * (C / 4)];
        p4 += 8 * (C / 4);
        __builtin_amdgcn_sched_barrier(0);         // all 8 loads issued first

#pragma unroll
        for (int r = 0; r < 8; ++r) {
            const int tc = tgt_lds[b * 8 + r];
            if ((tc >> 2) == tid) {
                const float4 v = (r == 0) ? v0 : (r == 1) ? v1 : (r == 2) ? v2
                               : (r == 3) ? v3 : (r == 4) ? v4 : (r == 5) ? v5
                               : (r == 6) ? v6 : v7;
                const int sel = tc & 3;
                sx += (sel == 0) ? v.x : (sel == 1) ? v.y : (sel == 2) ? v.z : v.w;
            }
        }

        a0 += __expf(v0.x) + __expf(v1.x) + __expf(v2.x) + __expf(v3.x)
            + __expf(v4.x) + __expf(v5.x) + __expf(v6.x) + __expf(v7.x);
        a1 += __expf(v0.y) + __expf(v1.y) + __expf(v2.y) + __expf(v3.y)
            + __expf(v4.y) + __expf(v5.y) + __expf(v6.y) + __expf(v7.y);
        a2 += __expf(v0.z) + __expf(v1.z) + __expf(v2.z) + __expf(v3.z)
            + __expf(v4.z) + __expf(v5.z) + __expf(v6.z) + __expf(v7.z);
        a3 += __expf(v0.w) + __expf(v1.w) + __expf(v2.w) + __expf(v3.w)
            + __expf(v4.w) + __expf(v5.w) + __expf(v6.w) + __expf(v7.w);
    }

    reinterpret_cast<float4*>(partial + (size_t)blockIdx.x * C)[tid] =
        make_float4(a0, a1, a2, a3);

#pragma unroll
    for (int off = 32; off > 0; off >>= 1)
        sx += __shfl_down(sx, off, 64);
    __shared__ float wsum[4];
    if ((tid & 63) == 0) wsum[tid >> 6] = sx;
    __syncthreads();
    if (tid == 0)
        sxArr[blockIdx.x] = wsum[0] + wsum[1] + wsum[2] + wsum[3];
}

// ---------------------------------------------------------------------------
// K2: reduce RB partials -> logS. 64 blocks own 16 columns each; a wave reads
// 8 rows x 64 B (full lines); 8 independent accumulator streams. Plain stores
// into owned columns — no atomics, no pre-zeroing. Dispatch boundary makes
// logS visible to K3.
__global__ __launch_bounds__(256) void colreduce_kernel(
    const float* __restrict__ partial, float* __restrict__ logS, int RB) {
    const int t  = threadIdx.x;
    const int cp = t & 7;          // column-pair slot within the 16-col group
    const int r0 = t >> 3;         // 0..31
    const int c0 = blockIdx.x * 16;
    const int eighth = RB / 8;     // 256 for RB=2048

    const float2* __restrict__ p2 =
        reinterpret_cast<const float2*>(partial) + (c0 >> 1) + cp;

    float2 a[8];
#pragma unroll
    for (int j = 0; j < 8; ++j) a[j] = make_float2(0.f, 0.f);
    for (int r = r0; r < eighth; r += 32) {
#pragma unroll
        for (int j = 0; j < 8; ++j) {
            const float2 v = p2[(size_t)(r + j * eighth) * (C / 2)];
            a[j].x += v.x;
            a[j].y += v.y;
        }
    }
    float2 s;
    s.x = ((a[0].x + a[1].x) + (a[2].x + a[3].x)) + ((a[4].x + a[5].x) + (a[6].x + a[7].x));
    s.y = ((a[0].y + a[1].y) + (a[2].y + a[3].y)) + ((a[4].y + a[5].y) + (a[6].y + a[7].y));
#pragma unroll
    for (int off = 8; off <= 32; off <<= 1) {
        s.x += __shfl_xor(s.x, off, 64);
        s.y += __shfl_xor(s.y, off, 64);
    }
    __shared__ float2 wred[4][8];
    if ((t & 63) < 8) wred[t >> 6][cp] = s;
    __syncthreads();
    if (t < 8) {
        const float vx = wred[0][t].x + wred[1][t].x + wred[2][t].x + wred[3][t].x;
        const float vy = wred[0][t].y + wred[1][t].y + wred[2][t].y + wred[3][t].y;
        logS[c0 + 2 * t]     = log2f(vx);
        logS[c0 + 2 * t + 1] = log2f(vy);
    }
}

// ---------------------------------------------------------------------------
// K3: wide gather + finalize. 256 blocks; each thread handles ONE target:
// coalesced tgt read + logS gather (4 KB table, L1-resident). Block-reduce ->
// gArr[b] (plain store + fence), arrival counter; last block sums the tiny
// gArr[256] + sxArr[RB] tail (~9 KB) and finalizes in double.
__global__ __launch_bounds__(256) void gather_finalize_kernel(
    const int* __restrict__ tgt, const float* __restrict__ logS,
    const float* __restrict__ sxArr, float* __restrict__ gArr,
    int* __restrict__ counter, float* __restrict__ out, int RB) {
    const int t = threadIdx.x;
    float v = logS[tgt[blockIdx.x * 256 + t]];
#pragma unroll
    for (int off = 32; off > 0; off >>= 1)
        v += __shfl_down(v, off, 64);
    __shared__ float wsum[4];
    if ((t & 63) == 0) wsum[t >> 6] = v;
    __syncthreads();

    __shared__ int last;
    if (t == 0) {
        gArr[blockIdx.x] = wsum[0] + wsum[1] + wsum[2] + wsum[3];
        __threadfence();           // make gArr visible before arrival
        const int old = __hip_atomic_fetch_add(counter, 1, __ATOMIC_ACQ_REL,
                                               __HIP_MEMORY_SCOPE_AGENT);
        last = (old == (int)gridDim.x - 1) ? 1 : 0;
    }
    __syncthreads();
    if (!last) return;

    // tiny tail: 256 + RB floats, full block parallel
    float gl = __hip_atomic_load(&gArr[t], __ATOMIC_RELAXED,
                                 __HIP_MEMORY_SCOPE_AGENT);
    float sx = 0.f;
    for (int i = t; i < RB; i += 256) sx += sxArr[i];
#pragma unroll
    for (int off = 32; off > 0; off >>= 1) {
        gl += __shfl_down(gl, off, 64);
        sx += __shfl_down(sx, off, 64);
    }
    __shared__ float r1[4], r2[4];
    if ((t & 63) == 0) { r1[t >> 6] = gl; r2[t >> 6] = sx; }
    __syncthreads();
    if (t == 0) {
        const double LOG2E = 1.4426950408889634;
        const double SumLogS = (double)(r1[0] + r1[1] + r1[2] + r1[3]);
        const double SumX    = (double)(r2[0] + r2[1] + r2[2] + r2[3]);
        const double termA   = -LOG2E * (double)C * (1.0 + (double)N * (double)EPS);
        const double total   = termA + LOG2E * SumX - SumLogS;
        out[0] = (float)(-total / ((double)N * (double)C));
    }
}

extern "C" void kernel_launch(void* const* d_in, const int* in_sizes, int n_in,
                              void* d_out, int out_size, void* d_ws, size_t ws_size,
                              hipStream_t stream) {
    const float* pred = (const float*)d_in[0];
    const int*   tgt  = (const int*)d_in[1];
    float* wsf     = (float*)d_ws;
    float* logS    = wsf;
    int*   counter = (int*)(wsf + 1024);
    float* sxArr   = wsf + 1088;               // up to 2048 entries
    float* gArr    = wsf + 3200;               // 256 entries
    float* partial = wsf + 4096;               // 16 KB offset, 16B-aligned
    const size_t base_bytes = 4096 * sizeof(float);

    int RB = 2048;
    while (RB > 512 && base_bytes + (size_t)RB * C * sizeof(float) > ws_size)
        RB >>= 1;

    if (RB >= 2048)
        colsum_partial_kernel<32><<<2048, 256, 0, stream>>>(pred, tgt, partial, sxArr, counter);
    else if (RB == 1024)
        colsum_partial_kernel<64><<<1024, 256, 0, stream>>>(pred, tgt, partial, sxArr, counter);
    else
        colsum_partial_kernel<128><<<512, 256, 0, stream>>>(pred, tgt, partial, sxArr, counter);

    colreduce_kernel<<<64, 256, 0, stream>>>(partial, logS, RB);
    gather_finalize_kernel<<<256, 256, 0, stream>>>(tgt, logS, sxArr, gArr,
                                                    counter, (float*)d_out, RB);
}

// Round 7
// 62.778 us; speedup vs baseline: 1.1433x; 1.0359x over previous
//
#include <hip/hip_runtime.h>
#include <math.h>

// pred [65536, 1024] f32, target [65536] int32
static constexpr int N = 65536;
static constexpr int C = 1024;
static constexpr float EPS = 1e-9f;

// Math (validated absmax==0.0 in R4/R5/R6):
//   total = termA + sum_t (log2e*x_t - log2(S[c_t]))
//   termA = -log2e * C * (1 + N*EPS)       (analytic: softmax cols sum to 1)
//   loss  = -total / (N*C)
//
// ws float layout (no pre-zeroing dispatch; no atomic accumulators):
//   [0..1023]   logS[C]        written by K2 (plain owned-column stores)
//   [1024]      counter        zeroed by K1 block 0; K3 arrival counter
//   [1088..1343] gArr[256]     per-block partial contributions (K3)
//   [4096..]    partial[RB][C] per-rowblock column partials (K1)

// ---------------------------------------------------------------------------
// K1: PURE streaming column partials of exp, software-pipelined.
// Thread t owns columns 4t..4t+3; block covers RPB consecutive rows.
// Each iteration issues the NEXT batch's 8 float4 loads, then consumes the
// current batch register-by-register (v0's exps before touching v1), so the
// compiler emits decreasing vmcnt(15..8) — the VMEM queue never drains to 0
// inside the loop. No target handling, no LDS, no atomics.
template <int RPB>
__global__ __launch_bounds__(256) void colsum_kernel(
    const float* __restrict__ pred, float* __restrict__ partial,
    int* __restrict__ counter) {
    const int tid = threadIdx.x;                   // 0..255
    if (blockIdx.x == 0 && tid == 0) *counter = 0; // for K3's arrival counter

    const float4* __restrict__ p4 =
        reinterpret_cast<const float4*>(pred) +
        (size_t)blockIdx.x * RPB * (C / 4) + tid;

    float a0 = 0.f, a1 = 0.f, a2 = 0.f, a3 = 0.f;

    // prologue: batch 0 in flight
    float4 v0 = p4[0 * (C / 4)];
    float4 v1 = p4[1 * (C / 4)];
    float4 v2 = p4[2 * (C / 4)];
    float4 v3 = p4[3 * (C / 4)];
    float4 v4 = p4[4 * (C / 4)];
    float4 v5 = p4[5 * (C / 4)];
    float4 v6 = p4[6 * (C / 4)];
    float4 v7 = p4[7 * (C / 4)];
    p4 += 8 * (C / 4);

#pragma unroll 1
    for (int b = 0; b < RPB / 8 - 1; ++b) {
        // issue next batch before consuming current one
        float4 w0 = p4[0 * (C / 4)];
        float4 w1 = p4[1 * (C / 4)];
        float4 w2 = p4[2 * (C / 4)];
        float4 w3 = p4[3 * (C / 4)];
        float4 w4 = p4[4 * (C / 4)];
        float4 w5 = p4[5 * (C / 4)];
        float4 w6 = p4[6 * (C / 4)];
        float4 w7 = p4[7 * (C / 4)];
        p4 += 8 * (C / 4);
        __builtin_amdgcn_sched_barrier(0);   // keep the 8 issues above the math

        // consume strictly in load order -> per-register vmcnt, no full drain
        a0 += __expf(v0.x); a1 += __expf(v0.y); a2 += __expf(v0.z); a3 += __expf(v0.w);
        a0 += __expf(v1.x); a1 += __expf(v1.y); a2 += __expf(v1.z); a3 += __expf(v1.w);
        a0 += __expf(v2.x); a1 += __expf(v2.y); a2 += __expf(v2.z); a3 += __expf(v2.w);
        a0 += __expf(v3.x); a1 += __expf(v3.y); a2 += __expf(v3.z); a3 += __expf(v3.w);
        a0 += __expf(v4.x); a1 += __expf(v4.y); a2 += __expf(v4.z); a3 += __expf(v4.w);
        a0 += __expf(v5.x); a1 += __expf(v5.y); a2 += __expf(v5.z); a3 += __expf(v5.w);
        a0 += __expf(v6.x); a1 += __expf(v6.y); a2 += __expf(v6.z); a3 += __expf(v6.w);
        a0 += __expf(v7.x); a1 += __expf(v7.y); a2 += __expf(v7.z); a3 += __expf(v7.w);

        v0 = w0; v1 = w1; v2 = w2; v3 = w3;
        v4 = w4; v5 = w5; v6 = w6; v7 = w7;
    }
    // epilogue: last batch
    a0 += __expf(v0.x); a1 += __expf(v0.y); a2 += __expf(v0.z); a3 += __expf(v0.w);
    a0 += __expf(v1.x); a1 += __expf(v1.y); a2 += __expf(v1.z); a3 += __expf(v1.w);
    a0 += __expf(v2.x); a1 += __expf(v2.y); a2 += __expf(v2.z); a3 += __expf(v2.w);
    a0 += __expf(v3.x); a1 += __expf(v3.y); a2 += __expf(v3.z); a3 += __expf(v3.w);
    a0 += __expf(v4.x); a1 += __expf(v4.y); a2 += __expf(v4.z); a3 += __expf(v4.w);
    a0 += __expf(v5.x); a1 += __expf(v5.y); a2 += __expf(v5.z); a3 += __expf(v5.w);
    a0 += __expf(v6.x); a1 += __expf(v6.y); a2 += __expf(v6.z); a3 += __expf(v6.w);
    a0 += __expf(v7.x); a1 += __expf(v7.y); a2 += __expf(v7.z); a3 += __expf(v7.w);

    reinterpret_cast<float4*>(partial + (size_t)blockIdx.x * C)[tid] =
        make_float4(a0, a1, a2, a3);
}

// ---------------------------------------------------------------------------
// K2: reduce RB partials -> logS. 64 blocks own 16 columns each; a wave reads
// 8 rows x 64 B (full lines); 8 independent accumulator streams. Plain stores
// into owned columns — no atomics. Dispatch boundary publishes logS to K3.
// (Validated R6.)
__global__ __launch_bounds__(256) void colreduce_kernel(
    const float* __restrict__ partial, float* __restrict__ logS, int RB) {
    const int t  = threadIdx.x;
    const int cp = t & 7;          // column-pair slot within the 16-col group
    const int r0 = t >> 3;         // 0..31
    const int c0 = blockIdx.x * 16;
    const int eighth = RB / 8;     // 256 for RB=2048

    const float2* __restrict__ p2 =
        reinterpret_cast<const float2*>(partial) + (c0 >> 1) + cp;

    float2 a[8];
#pragma unroll
    for (int j = 0; j < 8; ++j) a[j] = make_float2(0.f, 0.f);
    for (int r = r0; r < eighth; r += 32) {
#pragma unroll
        for (int j = 0; j < 8; ++j) {
            const float2 v = p2[(size_t)(r + j * eighth) * (C / 2)];
            a[j].x += v.x;
            a[j].y += v.y;
        }
    }
    float2 s;
    s.x = ((a[0].x + a[1].x) + (a[2].x + a[3].x)) + ((a[4].x + a[5].x) + (a[6].x + a[7].x));
    s.y = ((a[0].y + a[1].y) + (a[2].y + a[3].y)) + ((a[4].y + a[5].y) + (a[6].y + a[7].y));
#pragma unroll
    for (int off = 8; off <= 32; off <<= 1) {
        s.x += __shfl_xor(s.x, off, 64);
        s.y += __shfl_xor(s.y, off, 64);
    }
    __shared__ float2 wred[4][8];
    if ((t & 63) < 8) wred[t >> 6][cp] = s;
    __syncthreads();
    if (t < 8) {
        const float vx = wred[0][t].x + wred[1][t].x + wred[2][t].x + wred[3][t].x;
        const float vy = wred[0][t].y + wred[1][t].y + wred[2][t].y + wred[3][t].y;
        logS[c0 + 2 * t]     = log2f(vx);
        logS[c0 + 2 * t + 1] = log2f(vy);
    }
}

// ---------------------------------------------------------------------------
// K3: per-target contribution + finalize. 256 blocks x 256 threads; thread
// handles one target: coalesced tgt read, scattered pred[n,c] dword gather
// (65536 unique lines, fully parallel), logS gather (4 KB, cache-hot).
// Block-reduce -> gArr (plain store + fence), arrival counter; last block
// sums gArr[256] and finalizes in double. (Tail pattern validated R6.)
__global__ __launch_bounds__(256) void target_finalize_kernel(
    const int* __restrict__ tgt, const float* __restrict__ pred,
    const float* __restrict__ logS, float* __restrict__ gArr,
    int* __restrict__ counter, float* __restrict__ out) {
    const int t = threadIdx.x;
    const int n = blockIdx.x * 256 + t;
    const int c = tgt[n];
    const float x = pred[((size_t)n << 10) + c];      // C == 1024
    const float LOG2E_F = 1.4426950408889634f;
    float v = LOG2E_F * x - logS[c];
#pragma unroll
    for (int off = 32; off > 0; off >>= 1)
        v += __shfl_down(v, off, 64);
    __shared__ float wsum[4];
    if ((t & 63) == 0) wsum[t >> 6] = v;
    __syncthreads();

    __shared__ int last;
    if (t == 0) {
        gArr[blockIdx.x] = wsum[0] + wsum[1] + wsum[2] + wsum[3];
        __threadfence();           // publish gArr before arrival
        const int old = __hip_atomic_fetch_add(counter, 1, __ATOMIC_ACQ_REL,
                                               __HIP_MEMORY_SCOPE_AGENT);
        last = (old == (int)gridDim.x - 1) ? 1 : 0;
    }
    __syncthreads();
    if (!last) return;

    // tiny tail: 256 floats, full block parallel
    float gl = __hip_atomic_load(&gArr[t], __ATOMIC_RELAXED,
                                 __HIP_MEMORY_SCOPE_AGENT);
#pragma unroll
    for (int off = 32; off > 0; off >>= 1)
        gl += __shfl_down(gl, off, 64);
    __shared__ float r1[4];
    if ((t & 63) == 0) r1[t >> 6] = gl;
    __syncthreads();
    if (t == 0) {
        const double LOG2E = 1.4426950408889634;
        const double SumContrib = (double)(r1[0] + r1[1] + r1[2] + r1[3]);
        const double termA = -LOG2E * (double)C * (1.0 + (double)N * (double)EPS);
        const double total = termA + SumContrib;
        out[0] = (float)(-total / ((double)N * (double)C));
    }
}

extern "C" void kernel_launch(void* const* d_in, const int* in_sizes, int n_in,
                              void* d_out, int out_size, void* d_ws, size_t ws_size,
                              hipStream_t stream) {
    const float* pred = (const float*)d_in[0];
    const int*   tgt  = (const int*)d_in[1];
    float* wsf     = (float*)d_ws;
    float* logS    = wsf;
    int*   counter = (int*)(wsf + 1024);
    float* gArr    = wsf + 1088;               // 256 entries
    float* partial = wsf + 4096;               // 16 KB offset, 16B-aligned
    const size_t base_bytes = 4096 * sizeof(float);

    int RB = 2048;
    while (RB > 512 && base_bytes + (size_t)RB * C * sizeof(float) > ws_size)
        RB >>= 1;

    if (RB >= 2048)
        colsum_kernel<32><<<2048, 256, 0, stream>>>(pred, partial, counter);
    else if (RB == 1024)
        colsum_kernel<64><<<1024, 256, 0, stream>>>(pred, partial, counter);
    else
        colsum_kernel<128><<<512, 256, 0, stream>>>(pred, partial, counter);

    colreduce_kernel<<<64, 256, 0, stream>>>(partial, logS, RB);
    target_finalize_kernel<<<256, 256, 0, stream>>>(tgt, pred, logS, gArr,
                                                    counter, (float*)d_out);
}